// Round 3
// baseline (3079.743 us; speedup 1.0000x reference)
//
#include <hip/hip_runtime.h>
#include <stdint.h>

#define NKEYS 65536
#define DIM   1024
#define BQ    4096
#define DXV   768
#define DYV   256
#define THRESH 0.01f

#define BM 128
#define BN 128
#define BK 128   // fp8 bytes of K per tile

typedef __attribute__((ext_vector_type(4)))  int   int4v;
typedef __attribute__((ext_vector_type(8)))  int   int8v;
typedef __attribute__((ext_vector_type(16))) float f32x16;

#define SCALE1 0x7F7F7F7F  // e8m0 bytes = 127 -> 2^0 = 1.0

__device__ __forceinline__ void gl2lds16(const void* g, void* l) {
  __builtin_amdgcn_global_load_lds(
      (const __attribute__((address_space(1))) unsigned int*)g,
      (__attribute__((address_space(3))) unsigned int*)l, 16, 0, 0);
}

__device__ __forceinline__ unsigned int orderf(float f) {
  unsigned int u = __float_as_uint(f);
  return (u & 0x80000000u) ? ~u : (u | 0x80000000u);
}

// ---------------- prep: keys fp32 -> fp8 e4m3, fused row norms ----------------
__global__ void prep_keys(const float* __restrict__ keys,
                          unsigned char* __restrict__ K8,
                          float* __restrict__ knorm) {
  const int row = blockIdx.x;
  const int t = threadIdx.x;  // 256 threads x 4 floats
  const float4 v = ((const float4*)(keys + (size_t)row * DIM))[t];
  int p = __builtin_amdgcn_cvt_pk_fp8_f32(v.x, v.y, 0, false);
  p = __builtin_amdgcn_cvt_pk_fp8_f32(v.z, v.w, p, true);
  ((int*)(K8 + (size_t)row * DIM))[t] = p;
  float s = v.x * v.x + v.y * v.y + v.z * v.z + v.w * v.w;
  for (int m = 32; m; m >>= 1) s += __shfl_xor(s, m);
  __shared__ float red[4];
  const int lane = t & 63, wave = t >> 6;
  if (lane == 0) red[wave] = s;
  __syncthreads();
  if (t == 0) knorm[row] = red[0] + red[1] + red[2] + red[3];
}

// ---------------- prep: q = concat(X, Y) -> fp8 ----------------
__global__ void prep_q(const float* __restrict__ X, const float* __restrict__ Y,
                       unsigned char* __restrict__ Q8) {
  const int row = blockIdx.x;
  const int t = threadIdx.x;  // 256
  float4 v;
  int off;
  if (t < 192) { v = ((const float4*)(X + (size_t)row * DXV))[t]; off = t * 4; }
  else         { v = ((const float4*)(Y + (size_t)row * DYV))[t - 192]; off = DXV + (t - 192) * 4; }
  int p = __builtin_amdgcn_cvt_pk_fp8_f32(v.x, v.y, 0, false);
  p = __builtin_amdgcn_cvt_pk_fp8_f32(v.z, v.w, p, true);
  *(int*)(Q8 + (size_t)row * DIM + off) = p;
}

// ---------------- main: MX-fp8 MFMA GEMM + fused argmin ----------------
// score = knorm[n] - 2*dot(k8[n], q8[b]); per-b argmin merged via packed u64
// (ordered-float<<32 | n) atomicMin. 32x32x64 f8f6f4 MFMA, unit e8m0 scales.
// LDS 128B rows, 16B-chunk XOR swizzle c^=(r&7) on the staging SOURCE address
// (global_load_lds scatters linearly in LDS); reads apply the same XOR ->
// every wave64 ds_read_b128 hits each bank group exactly 8x (conflict-free).
__global__ __launch_bounds__(256, 4) void gemm_argmin(
    const unsigned char* __restrict__ K8,    // [NKEYS][DIM] fp8
    const unsigned char* __restrict__ Q8,    // [BQ][DIM] fp8
    const float* __restrict__ knorm,         // [NKEYS]
    unsigned long long* __restrict__ best) { // [BQ]
  __shared__ __align__(16) unsigned char As[BM * BK];  // q tile, 16 KB
  __shared__ __align__(16) unsigned char Bs[BN * BK];  // keys tile, 16 KB
  __shared__ unsigned long long cand[2][BM];

  const int bid = blockIdx.x;
  const int mtile = bid & 31;          // m-fastest: 32 blocks share a keys tile
  const int ntile = bid >> 5;
  const int tid = threadIdx.x;
  const int wave = tid >> 6;
  const int lane = tid & 63;
  const int wm = wave >> 1;
  const int wn = wave & 1;
  const int ln = lane & 31;            // m/n within a 32x32 frag
  const int h = lane >> 5;             // k-half select

  // staging: each 16KB tile = 16 chunks of 1KB; wave owns 4 chunks of each
  const char* agl[4]; const char* bgl[4];
  void* aldst[4]; void* bldst[4];
#pragma unroll
  for (int c = 0; c < 4; ++c) {
    const int chunk = wave * 4 + c;
    const int off = chunk * 1024 + lane * 16;
    const int r = off >> 7;                    // 128-byte rows
    const int kb = ((off >> 4) & 7) ^ (r & 7); // swizzled 16B chunk in row
    agl[c] = (const char*)Q8 + ((size_t)(mtile * BM + r) * DIM + kb * 16);
    bgl[c] = (const char*)K8 + ((size_t)(ntile * BN + r) * DIM + kb * 16);
    aldst[c] = (void*)(As + chunk * 1024);
    bldst[c] = (void*)(Bs + chunk * 1024);
  }

  f32x16 acc[2][2];
#pragma unroll
  for (int i = 0; i < 2; ++i)
#pragma unroll
    for (int j = 0; j < 2; ++j) acc[i][j] = (f32x16)0.0f;

  const int swz = ln & 7;

  for (int kt = 0; kt < DIM / BK; ++kt) {
    const size_t ko = (size_t)kt * BK;
#pragma unroll
    for (int c = 0; c < 4; ++c) gl2lds16(agl[c] + ko, aldst[c]);
#pragma unroll
    for (int c = 0; c < 4; ++c) gl2lds16(bgl[c] + ko, bldst[c]);
    __syncthreads();
#pragma unroll
    for (int ks = 0; ks < 2; ++ks) {
      const int c0 = (ks * 4 + 2 * h) ^ swz;  // first 16B chunk (swizzled)
      int8v a[2], b[2];
#pragma unroll
      for (int f = 0; f < 2; ++f) {
        const unsigned char* rowA = As + (wm * 64 + f * 32 + ln) * BK;
        const int4v lo = *(const int4v*)(rowA + c0 * 16);
        const int4v hi = *(const int4v*)(rowA + (c0 ^ 1) * 16);
        a[f][0] = lo[0]; a[f][1] = lo[1]; a[f][2] = lo[2]; a[f][3] = lo[3];
        a[f][4] = hi[0]; a[f][5] = hi[1]; a[f][6] = hi[2]; a[f][7] = hi[3];
      }
#pragma unroll
      for (int f = 0; f < 2; ++f) {
        const unsigned char* rowB = Bs + (wn * 64 + f * 32 + ln) * BK;
        const int4v lo = *(const int4v*)(rowB + c0 * 16);
        const int4v hi = *(const int4v*)(rowB + (c0 ^ 1) * 16);
        b[f][0] = lo[0]; b[f][1] = lo[1]; b[f][2] = lo[2]; b[f][3] = lo[3];
        b[f][4] = hi[0]; b[f][5] = hi[1]; b[f][6] = hi[2]; b[f][7] = hi[3];
      }
#pragma unroll
      for (int fm = 0; fm < 2; ++fm)
#pragma unroll
        for (int fn = 0; fn < 2; ++fn)
          acc[fm][fn] = __builtin_amdgcn_mfma_scale_f32_32x32x64_f8f6f4(
              a[fm], b[fn], acc[fm][fn], 0, 0,  // cbsz=fp8, blgp=fp8
              0, SCALE1, 0, SCALE1);
    }
    __syncthreads();
  }

  // ---- epilogue: per-m-row argmin over this block's 128-wide n range ----
  // 32x32 C/D: n = ln (per frag fn*32), m = (reg&3) + 8*(reg>>2) + 4*h
  const int nbase = ntile * BN + wn * 64 + ln;
  const float kn0 = knorm[nbase];
  const float kn1 = knorm[nbase + 32];

#pragma unroll
  for (int fm = 0; fm < 2; ++fm) {
#pragma unroll
    for (int reg = 0; reg < 16; ++reg) {
      const float v0 = kn0 - 2.0f * acc[fm][0][reg];
      const float v1 = kn1 - 2.0f * acc[fm][1][reg];
      float bv; int bn;
      if (v1 < v0) { bv = v1; bn = nbase + 32; } else { bv = v0; bn = nbase; }
      unsigned long long p =
          ((unsigned long long)orderf(bv) << 32) | (unsigned int)bn;
#pragma unroll
      for (int mask = 1; mask <= 16; mask <<= 1) {
        const unsigned long long q = __shfl_xor(p, mask);
        p = q < p ? q : p;
      }
      if (ln == 0)
        cand[wn][wm * 64 + fm * 32 + (reg & 3) + 8 * (reg >> 2) + 4 * h] = p;
    }
  }
  __syncthreads();
  if (tid < BM) {
    const unsigned long long a = cand[0][tid], b = cand[1][tid];
    const unsigned long long m = b < a ? b : a;
    atomicMin(&best[(size_t)mtile * BM + tid], m);
  }
}

// ---------------- finalize: exact fp32 d at winner, ball test, gather ----------------
__global__ void finalize(const unsigned long long* __restrict__ best,
                         const float* __restrict__ keys,
                         const float* __restrict__ values,
                         const int* __restrict__ pi,
                         const float* __restrict__ X,
                         const float* __restrict__ Y,
                         float* __restrict__ out) {
  const int b = blockIdx.x;
  const int t = threadIdx.x;  // 256
  const unsigned long long pk = best[b];
  const int n = (int)(unsigned int)(pk & 0xffffffffull);

  const float4 kv = ((const float4*)(keys + (size_t)n * DIM))[t];
  const float4 qv = (t < 192) ? ((const float4*)(X + (size_t)b * DXV))[t]
                              : ((const float4*)(Y + (size_t)b * DYV))[t - 192];
  const float dx = kv.x - qv.x, dy = kv.y - qv.y, dz = kv.z - qv.z, dw = kv.w - qv.w;
  float s = dx * dx + dy * dy + dz * dz + dw * dw;
  for (int m = 32; m; m >>= 1) s += __shfl_xor(s, m);
  __shared__ float red[4];
  __shared__ float flagS;
  const int lane = t & 63, wave = t >> 6;
  if (lane == 0) red[wave] = s;
  __syncthreads();
  if (t == 0)
    flagS = (red[0] + red[1] + red[2] + red[3] <= THRESH) ? 1.0f : 0.0f;
  __syncthreads();
  const float flag = flagS;
  const int row = pi[n];
  if (t < 192) {
    const float4 v = ((const float4*)(values + (size_t)row * DXV))[t];
    float4 o;
    o.x = v.x * flag; o.y = v.y * flag; o.z = v.z * flag; o.w = v.w * flag;
    ((float4*)(out + (size_t)b * DXV))[t] = o;
  }
}

extern "C" void kernel_launch(void* const* d_in, const int* in_sizes, int n_in,
                              void* d_out, int out_size, void* d_ws, size_t ws_size,
                              hipStream_t stream) {
  const float* keys   = (const float*)d_in[0];
  const float* values = (const float*)d_in[1];
  const int*   pi     = (const int*)d_in[2];
  const float* X      = (const float*)d_in[3];
  const float* Y      = (const float*)d_in[4];
  float* out = (float*)d_out;

  char* ws = (char*)d_ws;
  unsigned char* K8 = (unsigned char*)ws;                          // 64 MB
  unsigned char* Q8 = (unsigned char*)(ws + (size_t)NKEYS * DIM);  // 4 MB
  float* knorm = (float*)(ws + (size_t)NKEYS * DIM + (size_t)BQ * DIM);
  unsigned long long* best =
      (unsigned long long*)(ws + (size_t)NKEYS * DIM + (size_t)BQ * DIM +
                            (size_t)NKEYS * 4);

  hipMemsetAsync(best, 0xFF, (size_t)BQ * 8, stream);
  prep_keys<<<NKEYS, 256, 0, stream>>>(keys, K8, knorm);
  prep_q<<<BQ, 256, 0, stream>>>(X, Y, Q8);
  gemm_argmin<<<(NKEYS / BN) * (BQ / BM), 256, 0, stream>>>(K8, Q8, knorm, best);
  finalize<<<BQ, 256, 0, stream>>>(best, keys, values, pi, X, Y, out);
}